// Round 7
// baseline (1232.235 us; speedup 1.0000x reference)
//
#include <hip/hip_runtime.h>

// ---------------------------------------------------------------------------
// Round 7: widen wave tile to 64x128 (4 M-frags x 8 N-frags) => ds_read per
// MFMA drops 0.5 -> 0.375 (LDS pipe was the R6 ceiling), MFMA per barrier
// section doubles to 96/wave. BM=256 (TR=16), BN=128, 4 waves WM=4/WN=1.
// Same tap-row staged K-loop with register prefetch as R6.
// ---------------------------------------------------------------------------

typedef __attribute__((ext_vector_type(8))) short short8;
typedef __attribute__((ext_vector_type(4))) float f32x4;

__device__ __forceinline__ float b2f(ushort u) {
    return __uint_as_float(((unsigned)u) << 16);
}
__device__ __forceinline__ ushort f2b(float f) {   // round-to-nearest-even
    unsigned x = __float_as_uint(f);
    x += 0x7FFFu + ((x >> 16) & 1u);
    return (ushort)(x >> 16);
}
__device__ __forceinline__ ushort bmax(ushort a, ushort b) {
    return b2f(a) > b2f(b) ? a : b;
}

// ------------- repack weights [co][ci][t] f32 -> [t][cb][co][ci32] bf16 -----
__global__ __launch_bounds__(256)
void repack_w(const float* __restrict__ w, ushort* __restrict__ wp, int Cin, int Cout)
{
    int n = Cout * Cin * 9;
    int i = blockIdx.x * 256 + threadIdx.x;
    if (i >= n) return;
    int CBl = Cin / 32;
    int c   = i & 31;
    int co  = (i >> 5) % Cout;
    int cbt = i / (32 * Cout);
    int cb  = cbt % CBl;
    int t   = cbt / CBl;
    int ci  = cb * 32 + c;
    wp[i] = f2b(w[((size_t)co * Cin + ci) * 9 + t]);
}

// ------------- L1: 3->64 direct conv, fp32 NCHW in -> bf16 NHWC out ---------
__global__ __launch_bounds__(256)
void l1_conv(const float* __restrict__ in, const float* __restrict__ w,
             const float* __restrict__ bias, ushort* __restrict__ out)
{
    const int H = 384, W = 384;
    __shared__ float s[3][18][18];
    const int tid = threadIdx.x;
    const int tilesX = W / 16;
    const int x0 = (blockIdx.x % tilesX) * 16;
    const int y0 = (blockIdx.x / tilesX) * 16;
    const int b  = blockIdx.z;

    for (int i = tid; i < 3 * 18 * 18; i += 256) {
        int ci = i / (18 * 18);
        int r  = i % (18 * 18);
        int iy = r / 18, ix = r % 18;
        int gy = y0 - 1 + iy, gx = x0 - 1 + ix;
        float v = 0.f;
        if ((unsigned)gy < (unsigned)H && (unsigned)gx < (unsigned)W)
            v = in[((size_t)(b * 3 + ci) * H + gy) * W + gx];
        s[ci][iy][ix] = v;
    }
    __syncthreads();

    const int tx = tid & 15, ty = tid >> 4;
    float iv[3][3][3];
    #pragma unroll
    for (int ci = 0; ci < 3; ++ci)
        #pragma unroll
        for (int ky = 0; ky < 3; ++ky)
            #pragma unroll
            for (int kx = 0; kx < 3; ++kx)
                iv[ci][ky][kx] = s[ci][ty + ky][tx + kx];

    size_t pix = ((size_t)(b * H + y0 + ty) * W + x0 + tx);
    #pragma unroll
    for (int c4 = 0; c4 < 4; ++c4) {
        __align__(16) ushort ob[16];
        #pragma unroll
        for (int co = 0; co < 16; ++co) {
            int coG = c4 * 16 + co;
            float a = bias[coG];
            #pragma unroll
            for (int ci = 0; ci < 3; ++ci)
                #pragma unroll
                for (int ky = 0; ky < 3; ++ky)
                    #pragma unroll
                    for (int kx = 0; kx < 3; ++kx)
                        a = fmaf(w[((size_t)coG * 3 + ci) * 9 + ky * 3 + kx],
                                 iv[ci][ky][kx], a);
            a = a > 0.f ? a : 0.f;
            ob[co] = f2b(a);
        }
        *(short8*)&out[pix * 64 + c4 * 16]     = *(short8*)&ob[0];
        *(short8*)&out[pix * 64 + c4 * 16 + 8] = *(short8*)&ob[8];
    }
}

// ------------- 2x2 maxpool, bf16 NHWC ---------------------------------------
__global__ __launch_bounds__(256)
void maxpool_nhwc(const ushort* __restrict__ in, ushort* __restrict__ out,
                  int Ho, int Wo, int C)
{
    int n = 4 * Ho * Wo * (C / 8);
    int i = blockIdx.x * 256 + threadIdx.x;
    if (i >= n) return;
    int c8 = i % (C / 8);
    int pi = i / (C / 8);
    int x = pi % Wo, y = (pi / Wo) % Ho, b = pi / (Wo * Ho);
    int Hi = Ho * 2, Wi = Wo * 2;
    const ushort* p = in + ((size_t)(b * Hi + 2 * y) * Wi + 2 * x) * C + c8 * 8;
    short8 v00 = *(const short8*)p;
    short8 v01 = *(const short8*)(p + C);
    short8 v10 = *(const short8*)(p + (size_t)Wi * C);
    short8 v11 = *(const short8*)(p + (size_t)Wi * C + C);
    short8 o;
    #pragma unroll
    for (int j = 0; j < 8; ++j)
        o[j] = (short)bmax(bmax((ushort)v00[j], (ushort)v01[j]),
                           bmax((ushort)v10[j], (ushort)v11[j]));
    *(short8*)(out + (size_t)i * 8) = o;
}

// ------------- irregular pool (mask-gated 2x2 max, replicated), NHWC --------
__global__ __launch_bounds__(256)
void irpool_nhwc(const ushort* __restrict__ in, const int* __restrict__ mask,
                 ushort* __restrict__ out)
{
    const int C = 256, H = 96, Wd = 96;
    int n = 4 * H * Wd * (C / 8);
    int i = blockIdx.x * 256 + threadIdx.x;
    if (i >= n) return;
    int c8 = i % (C / 8);
    int pi = i / (C / 8);
    int x = pi % Wd, y = (pi / Wd) % H, b = pi / (Wd * H);
    int m = mask[(b * 48 + (y >> 1)) * 48 + (x >> 1)];
    short8 o;
    if (m) {
        int y0 = y & ~1, x0 = x & ~1;
        const ushort* p = in + ((size_t)(b * H + y0) * Wd + x0) * C + c8 * 8;
        short8 v00 = *(const short8*)p;
        short8 v01 = *(const short8*)(p + C);
        short8 v10 = *(const short8*)(p + (size_t)Wd * C);
        short8 v11 = *(const short8*)(p + (size_t)Wd * C + C);
        #pragma unroll
        for (int j = 0; j < 8; ++j)
            o[j] = (short)bmax(bmax((ushort)v00[j], (ushort)v01[j]),
                               bmax((ushort)v10[j], (ushort)v11[j]));
    } else {
        o = *(const short8*)(in + (size_t)pi * C + c8 * 8);
    }
    *(short8*)(out + (size_t)pi * C + c8 * 8) = o;
}

// ------------- implicit-GEMM conv3x3, tap-row staged, bf16 MFMA -------------
// Block = TRx16 output pixels, 256 threads = 4 waves.
// Wave tile = (MF*16) x (NF*16); WM x WN waves; BM=TR*16, BN=WN*NF*16.
// Per cb: A halo staged once; B staged per tap-ROW (3 taps, single buffer)
// with register prefetch of next row's B / next cb's A before the MFMA
// section. 6 barriers per cb, MF*NF*2*3 MFMAs per wave between barriers.
template<int TR, int BN, int MF, int NF, int WM, int WN,
         int CIN, int COUT, int H, int W, bool GCONV, bool FINAL>
__global__ __launch_bounds__(256)
void conv_mfma(const ushort* __restrict__ in, const ushort* __restrict__ wp,
               const float* __restrict__ bias, void* __restrict__ outv,
               const int* __restrict__ mask)
{
    constexpr int BM  = TR * 16;
    static_assert(WM * WN == 4, "4 waves");
    static_assert(WM * MF * 16 == BM, "M cover");
    static_assert(WN * NF * 16 == BN, "N cover");
    constexpr int CB  = CIN / 32;
    constexpr int HA  = GCONV ? 2 : 1;
    constexpr int CW  = 16 + 2 * HA;
    constexpr int CR  = TR + 2 * HA;
    constexpr int NCH = CR * CW;
    constexpr int NSA = NCH * 4;              // short8 chunks in sA
    constexpr int NSLA = (NSA + 255) / 256;
    constexpr int NSB = 3 * BN * 2;           // 16-ushort half-slots per row
    constexpr int NSLB = (NSB + 255) / 256;

    __shared__ __align__(16) ushort sA[NCH * 40];
    __shared__ __align__(16) ushort sB[3 * BN * 40];

    const int tid  = threadIdx.x;
    const int lane = tid & 63;
    const int wv   = tid >> 6;
    const int wm   = wv % WM;
    const int wn   = wv / WM;
    const int col  = lane & 15;
    const int quad = lane >> 4;

    const int tiles_x = W / 16, tiles_y = H / TR;
    int sp = blockIdx.x;
    const int b  = sp / (tiles_x * tiles_y);
    int rr = sp - b * tiles_x * tiles_y;
    const int ty = rr / tiles_x;
    const int tx = rr - ty * tiles_x;
    const int y0 = ty * TR, x0 = tx * 16;
    const int co0 = blockIdx.y * BN;

    int dA[MF], aoff[MF];
    #pragma unroll
    for (int mt = 0; mt < MF; ++mt) {
        dA[mt] = 1;
        if (GCONV) {
            int y = y0 + wm * MF + mt, x = x0 + col;
            dA[mt] = mask[(b * (H / 2) + (y >> 1)) * (W / 2) + (x >> 1)] ? 2 : 1;
        }
        aoff[mt] = (HA + wm * MF + mt) * CW + HA + col;
    }

    short8 pA[NSLA];
    short8 pB[NSLB][2];

    auto loadA = [&](int cb) {
        #pragma unroll
        for (int k = 0; k < NSLA; ++k) {
            int i = tid + k * 256;
            short8 v = {0, 0, 0, 0, 0, 0, 0, 0};
            if (NSA == NSLA * 256 || i < NSA) {
                int chunk = i >> 2, part = i & 3;
                int yy = chunk / CW, xx = chunk - yy * CW;
                int gy = y0 - HA + yy, gx = x0 - HA + xx;
                if ((unsigned)gy < (unsigned)H && (unsigned)gx < (unsigned)W)
                    v = *(const short8*)(in + ((size_t)(b * H + gy) * W + gx) * CIN
                                         + cb * 32 + part * 8);
            }
            pA[k] = v;
        }
    };
    auto storeA = [&]() {
        #pragma unroll
        for (int k = 0; k < NSLA; ++k) {
            int i = tid + k * 256;
            if (NSA == NSLA * 256 || i < NSA) {
                int chunk = i >> 2, part = i & 3;
                *(short8*)&sA[chunk * 40 + part * 8] = pA[k];
            }
        }
    };
    auto loadB = [&](int s) {
        int cb = s / 3, row = s % 3;
        #pragma unroll
        for (int k = 0; k < NSLB; ++k) {
            int i = tid + k * 256;
            if (NSB == NSLB * 256 || i < NSB) {
                int tl = i / (BN * 2);
                int r  = i % (BN * 2);
                int co = r >> 1, half = r & 1;
                const ushort* gp = wp
                    + ((size_t)((row * 3 + tl) * CB + cb) * COUT + co0 + co) * 32
                    + half * 16;
                pB[k][0] = *(const short8*)gp;
                pB[k][1] = *(const short8*)(gp + 8);
            }
        }
    };
    auto storeB = [&]() {
        #pragma unroll
        for (int k = 0; k < NSLB; ++k) {
            int i = tid + k * 256;
            if (NSB == NSLB * 256 || i < NSB) {
                int tl = i / (BN * 2);
                int r  = i % (BN * 2);
                int co = r >> 1, half = r & 1;
                *(short8*)&sB[(tl * BN + co) * 40 + half * 16]     = pB[k][0];
                *(short8*)&sB[(tl * BN + co) * 40 + half * 16 + 8] = pB[k][1];
            }
        }
    };

    f32x4 acc[MF][NF];
    #pragma unroll
    for (int i = 0; i < MF; ++i)
        #pragma unroll
        for (int j = 0; j < NF; ++j)
            acc[i][j] = (f32x4){0.f, 0.f, 0.f, 0.f};

    // prologue
    loadA(0);
    loadB(0);
    storeA();
    storeB();
    __syncthreads();

    for (int s = 0; s < 3 * CB; ++s) {
        const int row  = s % 3;
        const bool last = (s == 3 * CB - 1);
        if (!last) {
            loadB(s + 1);                 // global prefetch, lands at storeB
            if (row == 2) loadA(s / 3 + 1);
        }
        const int ky = row - 1;
        #pragma unroll
        for (int j = 0; j < 3; ++j) {
            const int kx = j - 1;
            short8 af[MF];
            #pragma unroll
            for (int i = 0; i < MF; ++i) {
                int chunk = aoff[i] + dA[i] * (ky * CW + kx);
                af[i] = *(const short8*)&sA[chunk * 40 + quad * 8];
            }
            #pragma unroll
            for (int nt = 0; nt < NF; ++nt) {
                short8 bf = *(const short8*)&sB[(j * BN + wn * NF * 16 + nt * 16 + col)
                                                * 40 + quad * 8];
                #pragma unroll
                for (int mt = 0; mt < MF; ++mt)
                    acc[mt][nt] = __builtin_amdgcn_mfma_f32_16x16x32_bf16(
                        af[mt], bf, acc[mt][nt], 0, 0, 0);
            }
        }
        if (!last) {
            __syncthreads();              // all reads of sA/sB done
            storeB();
            if (row == 2) storeA();
            __syncthreads();              // writes visible
        }
    }

    // ---- epilogue ----
    if (!FINAL) {
        ushort* outp = (ushort*)outv;
        #pragma unroll
        for (int mt = 0; mt < MF; ++mt) {
            int y = y0 + wm * MF + mt;
            #pragma unroll
            for (int nt = 0; nt < NF; ++nt) {
                int co = co0 + wn * NF * 16 + nt * 16 + col;
                float bv = bias[co];
                #pragma unroll
                for (int r2 = 0; r2 < 4; ++r2) {
                    int x = x0 + quad * 4 + r2;
                    float vv = acc[mt][nt][r2] + bv;
                    vv = vv > 0.f ? vv : 0.f;
                    outp[((size_t)(b * H + y) * W + x) * COUT + co] = f2b(vv);
                }
            }
        }
    } else {
        float* outp = (float*)outv;   // fp32 NCHW direct to d_out
        #pragma unroll
        for (int mt = 0; mt < MF; ++mt) {
            int y = y0 + wm * MF + mt;
            #pragma unroll
            for (int nt = 0; nt < NF; ++nt) {
                int co = co0 + wn * NF * 16 + nt * 16 + col;
                float bv = bias[co];
                f32x4 vv;
                #pragma unroll
                for (int r2 = 0; r2 < 4; ++r2) {
                    float z = acc[mt][nt][r2] + bv;
                    vv[r2] = z > 0.f ? z : 0.f;
                }
                *(f32x4*)&outp[((size_t)(b * COUT + co) * H + y) * W + x0 + quad * 4] = vv;
            }
        }
    }
}

// ---------------------------------------------------------------------------
extern "C" void kernel_launch(void* const* d_in, const int* in_sizes, int n_in,
                              void* d_out, int out_size, void* d_ws, size_t ws_size,
                              hipStream_t stream)
{
    const float* x    = (const float*)d_in[0];
    const int*   mask = (const int*)d_in[1];
    const float* Wt[10];
    const float* bs[10];
    for (int i = 0; i < 10; ++i) {
        Wt[i] = (const float*)d_in[2 + 2 * i];
        bs[i] = (const float*)d_in[3 + 2 * i];
    }

    const size_t ACT = (size_t)4 * 384 * 384 * 64;   // ushorts
    ushort* A  = (ushort*)d_ws;
    ushort* Bb = A + ACT;
    ushort* wpbase = Bb + ACT;

    static const int cins[10]  = {3, 64, 64, 128, 128, 256, 256, 256, 512, 512};
    static const int couts[10] = {64, 64, 128, 128, 256, 256, 256, 512, 512, 512};
    ushort* wp[10];
    size_t wo = 0;
    for (int l = 1; l < 10; ++l) {
        wp[l] = wpbase + wo;
        wo += (size_t)couts[l] * cins[l] * 9;
    }
    for (int l = 1; l < 10; ++l) {
        int n = couts[l] * cins[l] * 9;
        repack_w<<<(n + 255) / 256, 256, 0, stream>>>(Wt[l], wp[l], cins[l], couts[l]);
    }

    // L1: fp32 NCHW -> bf16 NHWC
    l1_conv<<<dim3(24 * 24, 1, 4), 256, 0, stream>>>(x, Wt[0], bs[0], A);

    // L2: 64->64 @384 (BM=256, BN=64, wave 64x64)
    conv_mfma<16, 64, 4, 4, 4, 1, 64, 64, 384, 384, false, false>
        <<<dim3(2304, 1), 256, 0, stream>>>(A, wp[1], bs[1], Bb, nullptr);
    maxpool_nhwc<<<(4 * 192 * 192 * 8 + 255) / 256, 256, 0, stream>>>(Bb, A, 192, 192, 64);

    // L3: 64->128 @192 (BM=256, BN=128, wave 64x128)
    conv_mfma<16, 128, 4, 8, 4, 1, 64, 128, 192, 192, false, false>
        <<<dim3(576, 1), 256, 0, stream>>>(A, wp[2], bs[2], Bb, nullptr);
    // L4: 128->128 @192
    conv_mfma<16, 128, 4, 8, 4, 1, 128, 128, 192, 192, false, false>
        <<<dim3(576, 1), 256, 0, stream>>>(Bb, wp[3], bs[3], A, nullptr);
    maxpool_nhwc<<<(4 * 96 * 96 * 16 + 255) / 256, 256, 0, stream>>>(A, Bb, 96, 96, 128);

    // L5: 128->256 @96
    conv_mfma<16, 128, 4, 8, 4, 1, 128, 256, 96, 96, false, false>
        <<<dim3(144, 2), 256, 0, stream>>>(Bb, wp[4], bs[4], A, nullptr);
    // L6: 256->256
    conv_mfma<16, 128, 4, 8, 4, 1, 256, 256, 96, 96, false, false>
        <<<dim3(144, 2), 256, 0, stream>>>(A, wp[5], bs[5], Bb, nullptr);
    // L7: 256->256
    conv_mfma<16, 128, 4, 8, 4, 1, 256, 256, 96, 96, false, false>
        <<<dim3(144, 2), 256, 0, stream>>>(Bb, wp[6], bs[6], A, nullptr);

    // irregular pool
    irpool_nhwc<<<(4 * 96 * 96 * 32 + 255) / 256, 256, 0, stream>>>(A, mask, Bb);

    // L8: gconv 256->512
    conv_mfma<16, 128, 4, 8, 4, 1, 256, 512, 96, 96, true, false>
        <<<dim3(144, 4), 256, 0, stream>>>(Bb, wp[7], bs[7], A, mask);
    // L9: gconv 512->512
    conv_mfma<16, 128, 4, 8, 4, 1, 512, 512, 96, 96, true, false>
        <<<dim3(144, 4), 256, 0, stream>>>(A, wp[8], bs[8], Bb, mask);
    // L10: gconv 512->512 -> fp32 NCHW d_out
    conv_mfma<16, 128, 4, 8, 4, 1, 512, 512, 96, 96, true, true>
        <<<dim3(144, 4), 256, 0, stream>>>(Bb, wp[9], bs[9], d_out, mask);

    (void)in_sizes; (void)n_in; (void)out_size; (void)ws_size;
}